// Round 1
// 242.635 us; speedup vs baseline: 1.0127x; 1.0127x over previous
//
#include <hip/hip_runtime.h>

// DropNorm: B=4096 rows, F=8192 features, fp32.
//   n = F/2; mu = sum(x*m)/n; sigma2 = sum(((x-mu)*m)^2)/(n-1)
//   out = gamma*m*(x-mu)*rsqrt(sigma2^2 + 1e-4) + beta   [sigma2 SQUARED: quirk]
//
// R4: remove the LDS row staging and the m01 float array; go register-resident.
//   - rocprof showed the top-5 dispatches are all harness poison-fills (~79us,
//     6.8 TB/s); dropnorm itself is <78.5us vs a 43us roofline (268MB @ 6.3TB/s)
//     -> latency/issue-bound, not BW-bound.
//   - mask is pre-packed into ONE uint32 per thread (bit 4k+j = feature
//     4*(tid+k*NT)+j): 1 dword load replaces 8 dwordx4 per row.
//   - xv stays in VGPRs across the barrier (no 32KB LDS round-trip: -16 DS
//     instr/thread); mg/beta loads are issued BEFORE the reduction so the
//     shuffle+barrier hides their L2 latency instead of serializing behind it.
//   - per-thread vmem: 40+16DS -> 26+0DS. VGPR ~ xv32+gv32+bv32+temps < 128
//     (launch_bounds(256,4) -> 4 blocks/CU; LDS now only 32B of partials).

constexpr int Bn = 4096;
constexpr int Fn = 8192;
constexpr int NT = 256;           // threads per block
constexpr int PT = Fn / (NT * 4); // 8 float4 per thread

typedef float f4 __attribute__((ext_vector_type(4)));

#define EPSV 1e-4f

__device__ inline int nzbytes(unsigned v) {
    return ((v & 0x000000ffu) != 0) + ((v & 0x0000ff00u) != 0) +
           ((v & 0x00ff0000u) != 0) + ((v & 0xff000000u) != 0);
}

// Prep: detect mask storage layout (uint8 bool vs int32), then materialize
//   mg[j]   = mask ? gamma[j] : 0.0                     (Fn floats)
//   bitpk[t]= packed mask bits for thread t of the main kernel:
//             bit (4k+j) = mask[4*(t + k*NT) + j]       (NT uint32)
// Detection: count nonzero among the first Fn BYTES. uint8 layout -> exactly
// Fn/2 = 4096; int32 layout -> those bytes span only 2048 ints -> count <= 2048.
__global__ __launch_bounds__(NT) void prep_kernel(const void* __restrict__ mask_raw,
                                                  const float* __restrict__ gamma,
                                                  unsigned* __restrict__ bitpk,
                                                  float* __restrict__ mg) {
    const unsigned char* mb = (const unsigned char*)mask_raw;
    const int* mi = (const int*)mask_raw;
    const uint4* mv = (const uint4*)mask_raw;
    const int tid = threadIdx.x;

    // vectorized nonzero-byte count over the first Fn bytes (512 uint4)
    int cnt = 0;
#pragma unroll
    for (int k = 0; k < Fn / 16 / NT; ++k) {   // 2 iterations
        const uint4 w = mv[tid + k * NT];
        cnt += nzbytes(w.x) + nzbytes(w.y) + nzbytes(w.z) + nzbytes(w.w);
    }
    for (int off = 32; off > 0; off >>= 1) cnt += __shfl_down(cnt, off, 64);

    __shared__ int wc[NT / 64];
    __shared__ int flag;
    if ((tid & 63) == 0) wc[tid >> 6] = cnt;
    __syncthreads();
    if (tid == 0) {
        int total = wc[0] + wc[1] + wc[2] + wc[3];
        flag = (total == Fn / 2) ? 1 : 0;   // 1 = uint8 layout, 0 = int32 layout
    }
    __syncthreads();
    const bool u8 = (flag != 0);

    // mg slice for this block
    const int per_block = Fn / gridDim.x;
    const int base = blockIdx.x * per_block;
    for (int j = base + tid; j < base + per_block; j += NT) {
        const bool on = u8 ? (mb[j] != 0) : (mi[j] != 0);
        mg[j] = on ? gamma[j] : 0.0f;
    }

    // packed per-thread mask word (block 0 only; mask bytes are L2-hot)
    if (blockIdx.x == 0) {
        unsigned w = 0;
#pragma unroll
        for (int k = 0; k < PT; ++k) {
#pragma unroll
            for (int j = 0; j < 4; ++j) {
                const int f = 4 * (tid + k * NT) + j;
                const bool on = u8 ? (mb[f] != 0) : (mi[f] != 0);
                w |= (on ? 1u : 0u) << (4 * k + j);
            }
        }
        bitpk[tid] = w;
    }
}

__global__ __launch_bounds__(NT, 4) void dropnorm_kernel(const float* __restrict__ x,
                                                         const unsigned* __restrict__ bitpk,
                                                         const float* __restrict__ mg,
                                                         const float* __restrict__ beta,
                                                         float* __restrict__ out) {
    __shared__ float rs[NT / 64], rss[NT / 64];

    const int row = blockIdx.x;
    const int tid = threadIdx.x;

    const f4* __restrict__ xr = (const f4*)(x + (size_t)row * Fn);
    const f4* __restrict__ g4 = (const f4*)mg;
    const f4* __restrict__ b4 = (const f4*)beta;
    f4* __restrict__ o4       = (f4*)(out + (size_t)row * Fn);

    // ---- issue ALL loads back-to-back: 1 + 8 + 8 + 8 vmem in flight before
    // any dependent use. mg/beta (L2-hot) latency is then hidden under the
    // accumulate + shuffle-reduce + barrier instead of a post-barrier stall.
    const unsigned mbits = bitpk[tid];      // L1-hot, same word every row
    f4 xv[PT];
    f4 gv[PT];
    f4 bv[PT];
#pragma unroll
    for (int k = 0; k < PT; ++k) xv[k] = xr[tid + k * NT];   // HBM, coalesced
#pragma unroll
    for (int k = 0; k < PT; ++k) gv[k] = g4[tid + k * NT];   // L2-hot
#pragma unroll
    for (int k = 0; k < PT; ++k) bv[k] = b4[tid + k * NT];   // L2-hot

    // ---- masked accumulate from registers (v_cndmask instead of mul-by-m01)
    float s = 0.f, ss = 0.f;
#pragma unroll
    for (int k = 0; k < PT; ++k) {
        const float a0 = ((mbits >> (4 * k + 0)) & 1u) ? xv[k].x : 0.f;
        const float a1 = ((mbits >> (4 * k + 1)) & 1u) ? xv[k].y : 0.f;
        const float a2 = ((mbits >> (4 * k + 2)) & 1u) ? xv[k].z : 0.f;
        const float a3 = ((mbits >> (4 * k + 3)) & 1u) ? xv[k].w : 0.f;
        s  += (a0 + a1) + (a2 + a3);
        ss += (a0 * a0 + a1 * a1) + (a2 * a2 + a3 * a3);
    }

    // 64-lane shuffle reduction, then cross-wave via 32B of LDS
    for (int off = 32; off > 0; off >>= 1) {
        s  += __shfl_down(s, off, 64);
        ss += __shfl_down(ss, off, 64);
    }
    if ((tid & 63) == 0) { rs[tid >> 6] = s; rss[tid >> 6] = ss; }
    __syncthreads();
    const float S  = (rs[0] + rs[1]) + (rs[2] + rs[3]);
    const float SS = (rss[0] + rss[1]) + (rss[2] + rss[3]);

    const float n  = (float)(Fn / 2);
    const float mu = S / n;
    // sum(diff^2) = sum(x^2 m) - n*mu^2   (sum(m) == n exactly)
    const float sigma2 = (SS - n * mu * mu) / (n - 1.0f);
    const float inv = rsqrtf(sigma2 * sigma2 + EPSV);  // quirk: sigma2 squared

    // ---- epilogue: pure VALU + stores, everything already in registers
#pragma unroll
    for (int k = 0; k < PT; ++k) {
        f4 o;
        o.x = gv[k].x * (xv[k].x - mu) * inv + bv[k].x;
        o.y = gv[k].y * (xv[k].y - mu) * inv + bv[k].y;
        o.z = gv[k].z * (xv[k].z - mu) * inv + bv[k].z;
        o.w = gv[k].w * (xv[k].w - mu) * inv + bv[k].w;
        __builtin_nontemporal_store(o, o4 + tid + k * NT);  // out never re-read
    }
}

extern "C" void kernel_launch(void* const* d_in, const int* in_sizes, int n_in,
                              void* d_out, int out_size, void* d_ws, size_t ws_size,
                              hipStream_t stream) {
    const float* x     = (const float*)d_in[0];
    const float* gamma = (const float*)d_in[1];
    const float* beta  = (const float*)d_in[2];
    const void*  mask  = d_in[3];
    float* out = (float*)d_out;

    float* mg = (float*)d_ws;                      // Fn floats
    unsigned* bitpk = (unsigned*)(mg + Fn);        // NT uint32

    prep_kernel<<<16, NT, 0, stream>>>(mask, gamma, bitpk, mg);
    dropnorm_kernel<<<Bn, NT, 0, stream>>>(x, bitpk, mg, beta, out);
}